// Round 3
// baseline (63.609 us; speedup 1.0000x reference)
//
#include <hip/hip_runtime.h>
#include <cmath>

#define EPSN 1e-12f

typedef _Float16 half8 __attribute__((ext_vector_type(8)));
typedef float f32x4 __attribute__((ext_vector_type(4)));

// ---------------------------------------------------------------------------
// scores_kernel: one block per (b,n), 256 threads = 4 waves.
// Prologue: normalize q rows (fp32), split f16 hi/lo, build A-fragment image
// in LDS (identical layout to validated round-2 qprep).
// Main: 4 K-chunks of 32; per chunk each thread stages its token's 32 raw
// fp32 values as f16 hi/lo B-fragments (fp32 sum-of-squares kept in reg);
// MFMA 16x16x32 with 3-term hi/lo product; inv-norm applied in epilogue.
// Raw barriers (lgkmcnt-only) keep prefetched global loads in flight.
// ---------------------------------------------------------------------------
__global__ __launch_bounds__(256, 3) void scores_kernel(
    const float* __restrict__ qr, const float* __restrict__ doc,
    const int* __restrict__ mask, float* __restrict__ scores) {
    __shared__ __align__(16) char Aimg[16384];   // [qt2][kstep4][hl2][1024B]
    __shared__ __align__(16) char Bimg[32768];   // [tile16][hl2][1024B]
    __shared__ float invS[256];
    __shared__ float wq[4][32];

    int t = threadIdx.x, bn = blockIdx.x, b = bn >> 4;
    int w = t >> 6, lane = t & 63, col = lane & 15;
    int mtile = t >> 4, mcol = t & 15;

    // ---- issue chunk-0 doc prefetch immediately (hides under prologue) ----
    const float4* dsrc = (const float4*)(doc + ((size_t)bn * 256 + t) * 128);
    float4 rA[8], rB[8];
#pragma unroll
    for (int i = 0; i < 8; ++i) rA[i] = dsrc[i];
    int mymask = mask[bn * 256 + t];

    // ---- q prologue: normalize + split + A-image ----
    {
        int row = t >> 3, jb = t & 7;            // 8 threads per q row
        const float4* qsrc = (const float4*)(qr + ((size_t)b * 32 + row) * 128 + jb * 16);
        float4 v[4];
#pragma unroll
        for (int i = 0; i < 4; ++i) v[i] = qsrc[i];
        float ss = 0.f;
#pragma unroll
        for (int i = 0; i < 4; ++i)
            ss += v[i].x*v[i].x + v[i].y*v[i].y + v[i].z*v[i].z + v[i].w*v[i].w;
        ss += __shfl_xor(ss, 1); ss += __shfl_xor(ss, 2); ss += __shfl_xor(ss, 4);
        float inv = 1.0f / fmaxf(sqrtf(ss), EPSN);
        int qt = row >> 4, kstep = jb >> 1;
#pragma unroll
        for (int kh = 0; kh < 2; ++kh) {
            float xs[8] = { v[2*kh].x,   v[2*kh].y,   v[2*kh].z,   v[2*kh].w,
                            v[2*kh+1].x, v[2*kh+1].y, v[2*kh+1].z, v[2*kh+1].w };
            half8 hh, hl;
#pragma unroll
            for (int e = 0; e < 8; ++e) {
                float x = xs[e] * inv;
                _Float16 h = (_Float16)x;
                hh[e] = h;
                hl[e] = (_Float16)(x - (float)h);
            }
            int quad = (jb & 1) * 2 + kh;
            int lanepos = (row & 15) + quad * 16;
            int base = ((qt * 4 + kstep) * 2) * 1024 + lanepos * 16;
            *(half8*)(Aimg + base)        = hh;
            *(half8*)(Aimg + base + 1024) = hl;
        }
    }
    asm volatile("s_waitcnt lgkmcnt(0)" ::: "memory");
    __builtin_amdgcn_s_barrier();

    f32x4 acc[2][4];
    f32x4 zero = {0.f, 0.f, 0.f, 0.f};
#pragma unroll
    for (int qt = 0; qt < 2; ++qt)
#pragma unroll
        for (int nt = 0; nt < 4; ++nt) acc[qt][nt] = zero;

    float ss_d = 0.f;

#define CHUNK(C, CUR, NXT, ISLAST) do {                                       \
    if (!(ISLAST)) {                                                          \
        _Pragma("unroll")                                                     \
        for (int i = 0; i < 8; ++i) NXT[i] = dsrc[(C + 1) * 8 + i];           \
    }                                                                         \
    _Pragma("unroll")                                                         \
    for (int i = 0; i < 8; ++i)                                               \
        ss_d += CUR[i].x*CUR[i].x + CUR[i].y*CUR[i].y                         \
              + CUR[i].z*CUR[i].z + CUR[i].w*CUR[i].w;                        \
    _Pragma("unroll")                                                         \
    for (int kg = 0; kg < 4; ++kg) {                                          \
        float xs[8] = { CUR[2*kg].x,   CUR[2*kg].y,   CUR[2*kg].z,   CUR[2*kg].w,   \
                        CUR[2*kg+1].x, CUR[2*kg+1].y, CUR[2*kg+1].z, CUR[2*kg+1].w };\
        half8 hh, hl;                                                         \
        _Pragma("unroll")                                                     \
        for (int e = 0; e < 8; ++e) {                                         \
            float x = xs[e];                                                  \
            _Float16 h = (_Float16)x;                                         \
            hh[e] = h;                                                        \
            hl[e] = (_Float16)(x - (float)h);                                 \
        }                                                                     \
        int bo = (mtile << 11) + (kg * 16 + mcol) * 16;                       \
        *(half8*)(Bimg + bo)        = hh;                                     \
        *(half8*)(Bimg + bo + 1024) = hl;                                     \
    }                                                                         \
    if (ISLAST) invS[t] = mymask ? (1.0f / fmaxf(sqrtf(ss_d), EPSN)) : 0.0f;  \
    asm volatile("s_waitcnt lgkmcnt(0)" ::: "memory");                        \
    __builtin_amdgcn_s_barrier();                                             \
    {                                                                         \
        int lo = lane << 4;                                                   \
        half8 a0h = *(const half8*)(Aimg + (((C) * 2 + 0) << 10) + lo);       \
        half8 a0l = *(const half8*)(Aimg + (((C) * 2 + 1) << 10) + lo);       \
        half8 a1h = *(const half8*)(Aimg + (((4 + (C)) * 2 + 0) << 10) + lo); \
        half8 a1l = *(const half8*)(Aimg + (((4 + (C)) * 2 + 1) << 10) + lo); \
        _Pragma("unroll")                                                     \
        for (int nt = 0; nt < 4; ++nt) {                                      \
            int tile = w * 4 + nt;                                            \
            half8 bh = *(const half8*)(Bimg + ((tile * 2 + 0) << 10) + lo);   \
            half8 bl = *(const half8*)(Bimg + ((tile * 2 + 1) << 10) + lo);   \
            acc[0][nt] = __builtin_amdgcn_mfma_f32_16x16x32_f16(a0l, bh, acc[0][nt], 0, 0, 0); \
            acc[0][nt] = __builtin_amdgcn_mfma_f32_16x16x32_f16(a0h, bl, acc[0][nt], 0, 0, 0); \
            acc[0][nt] = __builtin_amdgcn_mfma_f32_16x16x32_f16(a0h, bh, acc[0][nt], 0, 0, 0); \
            acc[1][nt] = __builtin_amdgcn_mfma_f32_16x16x32_f16(a1l, bh, acc[1][nt], 0, 0, 0); \
            acc[1][nt] = __builtin_amdgcn_mfma_f32_16x16x32_f16(a1h, bl, acc[1][nt], 0, 0, 0); \
            acc[1][nt] = __builtin_amdgcn_mfma_f32_16x16x32_f16(a1h, bh, acc[1][nt], 0, 0, 0); \
        }                                                                     \
    }                                                                         \
    asm volatile("s_waitcnt lgkmcnt(0)" ::: "memory");                        \
    __builtin_amdgcn_s_barrier();                                             \
} while (0)

    CHUNK(0, rA, rB, false);
    CHUNK(1, rB, rA, false);
    CHUNK(2, rA, rB, false);
    CHUNK(3, rB, rA, true);
#undef CHUNK

    // ---- epilogue: inv-norm, max over tokens, sum over q (validated r2) ----
    float inv[4];
#pragma unroll
    for (int nt = 0; nt < 4; ++nt) inv[nt] = invS[w * 64 + nt * 16 + col];
    float m8[8];
#pragma unroll
    for (int qt = 0; qt < 2; ++qt)
#pragma unroll
        for (int rg = 0; rg < 4; ++rg) {
            float mv = -INFINITY;
#pragma unroll
            for (int nt = 0; nt < 4; ++nt) mv = fmaxf(mv, acc[qt][nt][rg] * inv[nt]);
            m8[qt * 4 + rg] = mv;
        }
#pragma unroll
    for (int off = 1; off < 16; off <<= 1)
#pragma unroll
        for (int i = 0; i < 8; ++i) m8[i] = fmaxf(m8[i], __shfl_xor(m8[i], off));
    if (col == 0) {
        int rg = lane >> 4;   // C/D row group: row = rg*4 + reg
#pragma unroll
        for (int qt = 0; qt < 2; ++qt)
#pragma unroll
            for (int rr = 0; rr < 4; ++rr) wq[w][qt * 16 + rg * 4 + rr] = m8[qt * 4 + rr];
    }
    __syncthreads();
    if (w == 0) {
        float v = 0.f;
        if (lane < 32)
            v = fmaxf(fmaxf(wq[0][lane], wq[1][lane]), fmaxf(wq[2][lane], wq[3][lane]));
#pragma unroll
        for (int off = 1; off < 64; off <<= 1) v += __shfl_xor(v, off);
        if (lane == 0) scores[bn] = v;
    }
}

// ---------------------------------------------------------------------------
// loss_kernel: all 64*256 pairs in one 1024-thread block.
// ---------------------------------------------------------------------------
__global__ __launch_bounds__(1024) void loss_kernel(const float* __restrict__ scores,
                                                    const float* __restrict__ labels,
                                                    float* __restrict__ out) {
    __shared__ float wsum[16];
    int t = threadIdx.x;
    float total = 0.f;
#pragma unroll
    for (int it = 0; it < 16; ++it) {
        int p = t + it * 1024;
        int b = p >> 8, ij = p & 255, i = ij >> 4, j = ij & 15;
        float ysi = labels[b * 32 + i], ysj = labels[b * 32 + j];
        if (ysi - ysj > 0.f) {
            float wgt = fabsf(labels[b * 32 + 16 + i] - labels[b * 32 + 16 + j]);
            float d = (i <= j) ? (scores[b * 16 + i] - scores[b * 16 + j]) : 0.f;
            total += log1pf(expf(-d)) * wgt;
        }
    }
#pragma unroll
    for (int off = 1; off < 64; off <<= 1) total += __shfl_xor(total, off);
    int lane = t & 63;
    if (lane == 0) wsum[t >> 6] = total;
    __syncthreads();
    if (t < 64) {
        float v = (t < 16) ? wsum[t] : 0.f;
#pragma unroll
        for (int off = 1; off < 64; off <<= 1) v += __shfl_xor(v, off);
        if (t == 0) out[0] = v;
    }
}

// ---------------------------------------------------------------------------
extern "C" void kernel_launch(void* const* d_in, const int* in_sizes, int n_in,
                              void* d_out, int out_size, void* d_ws, size_t ws_size,
                              hipStream_t stream) {
    const float* qr     = (const float*)d_in[0];   // (64,32,128) f32
    const float* doc    = (const float*)d_in[1];   // (64,16,256,128) f32
    const int*   dmask  = (const int*)d_in[2];     // (64,16,256) i32
    const float* labels = (const float*)d_in[3];   // (64,32) f32
    float* out = (float*)d_out;

    float* scores = (float*)d_ws;                  // 1024 f32

    scores_kernel<<<1024, 256, 0, stream>>>(qr, doc, dmask, scores);
    loss_kernel<<<1, 1024, 0, stream>>>(scores, labels, out);
}

// Round 4
// 34.919 us; speedup vs baseline: 1.8216x; 1.8216x over previous
//
#include <hip/hip_runtime.h>
#include <cmath>

#define EPSN 1e-12f

typedef _Float16 half8 __attribute__((ext_vector_type(8)));
typedef float f32x4 __attribute__((ext_vector_type(4)));

// ---------------------------------------------------------------------------
// scores_kernel: one block per (b, n, half). 256 threads = 4 waves.
// Block handles 128 doc tokens. Thread (tok = t&127, kh = t>>7) owns 64B of
// its token's row per K-chunk (4 float4s). 4 K-chunks of 32; f16 hi/lo
// 3-term MFMA (validated round 2); fp32 sum-of-squares in regs, inv-norm in
// epilogue. Lean register ping-pong prefetch (16 VGPRs) + lgkmcnt-only
// barriers keep next chunk's loads in flight across both barriers.
// Output: pmax[g*32 + q] = per-q max over this block's 128 tokens.
// ---------------------------------------------------------------------------
__global__ __launch_bounds__(256, 4) void scores_kernel(
    const float* __restrict__ qr, const float* __restrict__ doc,
    const int* __restrict__ mask, float* __restrict__ pmax) {
    __shared__ __align__(16) char Aimg[16384];   // [qt2][kstep4][hl2][1024B]
    __shared__ __align__(16) char Bimg[16384];   // [tile8][hl2][kg4][col16][16B]
    __shared__ float ssPart[256];
    __shared__ float invS[128];
    __shared__ float wq[4][32];

    int t = threadIdx.x, g = blockIdx.x;
    int bn = g >> 1, h = g & 1, b = g >> 5;
    int w = t >> 6, lane = t & 63, col = lane & 15;
    int tok = t & 127, kh = t >> 7;

    // ---- issue chunk-0 prefetch immediately ----
    const float4* dsrc = (const float4*)(doc + ((size_t)bn * 256 + h * 128 + tok) * 128) + kh * 4;
    float4 rA0 = dsrc[0], rA1 = dsrc[1], rA2 = dsrc[2], rA3 = dsrc[3];
    float4 rB0, rB1, rB2, rB3;
    int mymask = 0;
    if (t < 128) mymask = mask[bn * 256 + h * 128 + t];

    // ---- q prologue: normalize + f16 hi/lo split + A-image (validated) ----
    {
        int row = t >> 3, jb = t & 7;
        const float4* qsrc = (const float4*)(qr + ((size_t)b * 32 + row) * 128 + jb * 16);
        float4 v[4];
#pragma unroll
        for (int i = 0; i < 4; ++i) v[i] = qsrc[i];
        float ss = 0.f;
#pragma unroll
        for (int i = 0; i < 4; ++i)
            ss += v[i].x*v[i].x + v[i].y*v[i].y + v[i].z*v[i].z + v[i].w*v[i].w;
        ss += __shfl_xor(ss, 1); ss += __shfl_xor(ss, 2); ss += __shfl_xor(ss, 4);
        float inv = 1.0f / fmaxf(sqrtf(ss), EPSN);
        int qt = row >> 4, kstep = jb >> 1;
#pragma unroll
        for (int khh = 0; khh < 2; ++khh) {
            float xs[8] = { v[2*khh].x,   v[2*khh].y,   v[2*khh].z,   v[2*khh].w,
                            v[2*khh+1].x, v[2*khh+1].y, v[2*khh+1].z, v[2*khh+1].w };
            half8 hh, hl;
#pragma unroll
            for (int e = 0; e < 8; ++e) {
                float x = xs[e] * inv;
                _Float16 hv = (_Float16)x;
                hh[e] = hv;
                hl[e] = (_Float16)(x - (float)hv);
            }
            int quad = (jb & 1) * 2 + khh;
            int base = ((qt * 4 + kstep) * 2) * 1024 + ((row & 15) + quad * 16) * 16;
            *(half8*)(Aimg + base)        = hh;
            *(half8*)(Aimg + base + 1024) = hl;
        }
    }
    asm volatile("s_waitcnt lgkmcnt(0)" ::: "memory");
    __builtin_amdgcn_s_barrier();

    f32x4 acc[2][2];
    f32x4 zero = {0.f, 0.f, 0.f, 0.f};
    acc[0][0] = zero; acc[0][1] = zero; acc[1][0] = zero; acc[1][1] = zero;
    float ss_d = 0.f;

    int tile8 = tok >> 4;
    int bo_base = tile8 * 2048 + (2 * kh) * 256 + (tok & 15) * 16;

#define CHUNK(C, P0, P1, P2, P3, N0, N1, N2, N3, ISLAST) do {                 \
    if (!(ISLAST)) {                                                          \
        N0 = dsrc[(C + 1) * 8 + 0]; N1 = dsrc[(C + 1) * 8 + 1];               \
        N2 = dsrc[(C + 1) * 8 + 2]; N3 = dsrc[(C + 1) * 8 + 3];               \
    }                                                                         \
    ss_d += P0.x*P0.x + P0.y*P0.y + P0.z*P0.z + P0.w*P0.w;                    \
    ss_d += P1.x*P1.x + P1.y*P1.y + P1.z*P1.z + P1.w*P1.w;                    \
    ss_d += P2.x*P2.x + P2.y*P2.y + P2.z*P2.z + P2.w*P2.w;                    \
    ss_d += P3.x*P3.x + P3.y*P3.y + P3.z*P3.z + P3.w*P3.w;                    \
    {                                                                         \
        float xa[8] = { P0.x, P0.y, P0.z, P0.w, P1.x, P1.y, P1.z, P1.w };     \
        float xb[8] = { P2.x, P2.y, P2.z, P2.w, P3.x, P3.y, P3.z, P3.w };     \
        half8 hha, hla, hhb, hlb;                                             \
        _Pragma("unroll")                                                     \
        for (int e = 0; e < 8; ++e) {                                         \
            float x = xa[e]; _Float16 hv = (_Float16)x;                       \
            hha[e] = hv; hla[e] = (_Float16)(x - (float)hv);                  \
            float y = xb[e]; _Float16 hw = (_Float16)y;                       \
            hhb[e] = hw; hlb[e] = (_Float16)(y - (float)hw);                  \
        }                                                                     \
        *(half8*)(Bimg + bo_base)              = hha;                         \
        *(half8*)(Bimg + bo_base + 1024)       = hla;                         \
        *(half8*)(Bimg + bo_base + 256)        = hhb;                         \
        *(half8*)(Bimg + bo_base + 256 + 1024) = hlb;                         \
    }                                                                         \
    if (ISLAST) ssPart[t] = ss_d;                                             \
    asm volatile("s_waitcnt lgkmcnt(0)" ::: "memory");                        \
    __builtin_amdgcn_s_barrier();                                             \
    if ((ISLAST) && t < 128) {                                                \
        float sst = ssPart[t] + ssPart[t + 128];                              \
        invS[t] = mymask ? (1.0f / fmaxf(sqrtf(sst), EPSN)) : 0.0f;           \
    }                                                                         \
    {                                                                         \
        int lo = lane << 4;                                                   \
        half8 a0h = *(const half8*)(Aimg + (((C) * 2 + 0) << 10) + lo);       \
        half8 a0l = *(const half8*)(Aimg + (((C) * 2 + 1) << 10) + lo);       \
        half8 a1h = *(const half8*)(Aimg + (((4 + (C)) * 2 + 0) << 10) + lo); \
        half8 a1l = *(const half8*)(Aimg + (((4 + (C)) * 2 + 1) << 10) + lo); \
        _Pragma("unroll")                                                     \
        for (int nt = 0; nt < 2; ++nt) {                                      \
            int tile = w * 2 + nt;                                            \
            half8 bh = *(const half8*)(Bimg + tile * 2048 + lo);              \
            half8 bl = *(const half8*)(Bimg + tile * 2048 + 1024 + lo);       \
            acc[0][nt] = __builtin_amdgcn_mfma_f32_16x16x32_f16(a0l, bh, acc[0][nt], 0, 0, 0); \
            acc[0][nt] = __builtin_amdgcn_mfma_f32_16x16x32_f16(a0h, bl, acc[0][nt], 0, 0, 0); \
            acc[0][nt] = __builtin_amdgcn_mfma_f32_16x16x32_f16(a0h, bh, acc[0][nt], 0, 0, 0); \
            acc[1][nt] = __builtin_amdgcn_mfma_f32_16x16x32_f16(a1l, bh, acc[1][nt], 0, 0, 0); \
            acc[1][nt] = __builtin_amdgcn_mfma_f32_16x16x32_f16(a1h, bl, acc[1][nt], 0, 0, 0); \
            acc[1][nt] = __builtin_amdgcn_mfma_f32_16x16x32_f16(a1h, bh, acc[1][nt], 0, 0, 0); \
        }                                                                     \
    }                                                                         \
    asm volatile("s_waitcnt lgkmcnt(0)" ::: "memory");                        \
    __builtin_amdgcn_s_barrier();                                             \
} while (0)

    CHUNK(0, rA0, rA1, rA2, rA3, rB0, rB1, rB2, rB3, false);
    CHUNK(1, rB0, rB1, rB2, rB3, rA0, rA1, rA2, rA3, false);
    CHUNK(2, rA0, rA1, rA2, rA3, rB0, rB1, rB2, rB3, false);
    CHUNK(3, rB0, rB1, rB2, rB3, rA0, rA1, rA2, rA3, true);
#undef CHUNK

    // ---- epilogue: inv-norm, max over this block's 128 tokens ----
    float inv0 = invS[w * 32 + col];
    float inv1 = invS[w * 32 + 16 + col];
    float m8[8];
#pragma unroll
    for (int qt = 0; qt < 2; ++qt)
#pragma unroll
        for (int rr = 0; rr < 4; ++rr)
            m8[qt * 4 + rr] = fmaxf(acc[qt][0][rr] * inv0, acc[qt][1][rr] * inv1);
#pragma unroll
    for (int off = 1; off < 16; off <<= 1)
#pragma unroll
        for (int i = 0; i < 8; ++i) m8[i] = fmaxf(m8[i], __shfl_xor(m8[i], off));
    if (col == 0) {
        int rg = lane >> 4;   // C/D: row = (lane>>4)*4 + reg (m89-verified)
#pragma unroll
        for (int qt = 0; qt < 2; ++qt)
#pragma unroll
            for (int rr = 0; rr < 4; ++rr) wq[w][qt * 16 + rg * 4 + rr] = m8[qt * 4 + rr];
    }
    __syncthreads();
    if (w == 0 && lane < 32) {
        float v = fmaxf(fmaxf(wq[0][lane], wq[1][lane]), fmaxf(wq[2][lane], wq[3][lane]));
        pmax[(size_t)g * 32 + lane] = v;
    }
}

// ---------------------------------------------------------------------------
// lossb_kernel: one block per b. Combines the 2 half-block maxes into scores
// then computes this b's 256 pair losses.
// ---------------------------------------------------------------------------
__global__ __launch_bounds__(256) void lossb_kernel(const float* __restrict__ pmax,
                                                    const float* __restrict__ labels,
                                                    float* __restrict__ partial) {
    __shared__ float pmL[1024];
    __shared__ float sc[16], ysS[16], idxS[16];
    __shared__ float wsum[4];
    int b = blockIdx.x, t = threadIdx.x;
    ((float4*)pmL)[t] = ((const float4*)(pmax + (size_t)b * 1024))[t];
    if (t < 16) { ysS[t] = labels[b * 32 + t]; idxS[t] = labels[b * 32 + 16 + t]; }
    __syncthreads();
    {
        int n = t >> 4, qq = t & 15;
        // rows 2n (half 0), 2n+1 (half 1); q = qq and qq+16
        float v = fmaxf(pmL[n * 64 + qq],      pmL[n * 64 + 32 + qq])
                + fmaxf(pmL[n * 64 + 16 + qq], pmL[n * 64 + 48 + qq]);
        v += __shfl_xor(v, 1); v += __shfl_xor(v, 2);
        v += __shfl_xor(v, 4); v += __shfl_xor(v, 8);
        if (qq == 0) sc[n] = v;
    }
    __syncthreads();
    int i = t >> 4, j = t & 15;
    float v = 0.f;
    if (ysS[i] - ysS[j] > 0.f) {
        float wgt = fabsf(idxS[i] - idxS[j]);
        float d = (i <= j) ? (sc[i] - sc[j]) : 0.f;
        v = log1pf(expf(-d)) * wgt;
    }
#pragma unroll
    for (int off = 1; off < 64; off <<= 1) v += __shfl_xor(v, off);
    int lane = t & 63;
    if (lane == 0) wsum[t >> 6] = v;
    __syncthreads();
    if (t == 0) partial[b] = wsum[0] + wsum[1] + wsum[2] + wsum[3];
}

__global__ void lossfin_kernel(const float* __restrict__ partial, float* __restrict__ out) {
    int t = threadIdx.x;   // 64 threads
    float v = partial[t];
#pragma unroll
    for (int off = 1; off < 64; off <<= 1) v += __shfl_xor(v, off);
    if (t == 0) out[0] = v;
}

// ---------------------------------------------------------------------------
extern "C" void kernel_launch(void* const* d_in, const int* in_sizes, int n_in,
                              void* d_out, int out_size, void* d_ws, size_t ws_size,
                              hipStream_t stream) {
    const float* qr     = (const float*)d_in[0];   // (64,32,128) f32
    const float* doc    = (const float*)d_in[1];   // (64,16,256,128) f32
    const int*   dmask  = (const int*)d_in[2];     // (64,16,256) i32
    const float* labels = (const float*)d_in[3];   // (64,32) f32
    float* out = (float*)d_out;

    float* pmax    = (float*)d_ws;                 // 2048*32 f32 = 256 KB
    float* partial = pmax + 2048 * 32;             // 64 f32

    scores_kernel<<<2048, 256, 0, stream>>>(qr, doc, dmask, pmax);
    lossb_kernel<<<64, 256, 0, stream>>>(pmax, labels, partial);
    lossfin_kernel<<<1, 64, 0, stream>>>(partial, out);
}